// Round 5
// baseline (269.853 us; speedup 1.0000x reference)
//
#include <hip/hip_runtime.h>
#include <hip/hip_bf16.h>
#include <stdint.h>

// Problem constants (all static per reference)
#define TOK   16384
#define DIMM  512
#define NHEAD 16
#define HDIM  32
#define HID   2048
#define NWIN  256
#define WLEN  64
#define EPSV  1e-5f
#define SCL   0.17677669529663687f   // 32^-0.5

typedef __hip_bfloat16 bf16;
typedef __attribute__((ext_vector_type(8))) __bf16 bf16x8;
typedef __attribute__((ext_vector_type(4))) float f32x4;

// window-order row r (win*64 + l, shifted coords) -> original token row
__device__ __forceinline__ int remap_row(int r){
  int win = r >> 6, l = r & 63;
  int gh = ((win >> 4) << 3) + (l >> 3);
  int gw = ((win & 15) << 3) + (l & 7);
  int oh = (gh + 4) & 127, ow = (gw + 4) & 127;
  return (oh << 7) + ow;
}

// Swin shift-mask region id (slices: [0,120) [120,124) [124,128) on each axis)
__device__ __forceinline__ int region_of(int win, int l){
  int gh = ((win >> 4) << 3) + (l >> 3);
  int gw = ((win & 15) << 3) + (l & 7);
  int rh = (gh < 120) ? 0 : ((gh < 124) ? 1 : 2);
  int rw = (gw < 120) ? 0 : ((gw < 124) ? 1 : 2);
  return rh * 3 + rw;
}

__device__ __forceinline__ void gl_lds16(const bf16* g, bf16* l){
  __builtin_amdgcn_global_load_lds((const __attribute__((address_space(1))) void*)g,
                                   (__attribute__((address_space(3))) void*)l, 16, 0, 0);
}

// ---------------- weight fp32 -> bf16 convert (4 ranges, contiguous dst) -------------
__global__ __launch_bounds__(256) void convert_w(const float* __restrict__ a,
                                                 const float* __restrict__ b,
                                                 const float* __restrict__ c,
                                                 const float* __restrict__ d,
                                                 bf16* __restrict__ dst){
  int e = (blockIdx.x * 256 + threadIdx.x) * 4;
  float4 v;
  if (e < 786432)        v = *(const float4*)(a + e);
  else if (e < 1048576)  v = *(const float4*)(b + (e - 786432));
  else if (e < 2097152)  v = *(const float4*)(c + (e - 1048576));
  else                   v = *(const float4*)(d + (e - 2097152));
  union { bf16 h[4]; int2 q; } u;
  u.h[0] = __float2bfloat16(v.x); u.h[1] = __float2bfloat16(v.y);
  u.h[2] = __float2bfloat16(v.z); u.h[3] = __float2bfloat16(v.w);
  *(int2*)(dst + e) = u.q;
}

// ---------------- LayerNorm (one wave per row), optional shift+window remap ----------
template<bool REMAP>
__global__ __launch_bounds__(256) void ln_kernel(const float* __restrict__ in,
    const float* __restrict__ w, const float* __restrict__ b, bf16* __restrict__ outp)
{
  const int wave = threadIdx.x >> 6, lane = threadIdx.x & 63;
  const int r = blockIdx.x * 4 + wave;
  const int src = REMAP ? remap_row(r) : r;
  const float4* row = (const float4*)(in + (size_t)src * DIMM);
  float4 v0 = row[lane*2], v1 = row[lane*2 + 1];
  float sm = v0.x+v0.y+v0.z+v0.w + v1.x+v1.y+v1.z+v1.w;
  float sq = v0.x*v0.x+v0.y*v0.y+v0.z*v0.z+v0.w*v0.w
           + v1.x*v1.x+v1.y*v1.y+v1.z*v1.z+v1.w*v1.w;
  #pragma unroll
  for (int off = 1; off < 64; off <<= 1){
    sm += __shfl_xor(sm, off);
    sq += __shfl_xor(sq, off);
  }
  const float mean = sm * (1.f/512.f);
  const float rstd = rsqrtf(sq*(1.f/512.f) - mean*mean + EPSV);
  const float4* wp = (const float4*)w; const float4* bp = (const float4*)b;
  float4 w0 = wp[lane*2], w1 = wp[lane*2+1], b0 = bp[lane*2], b1 = bp[lane*2+1];
  union { bf16 h[8]; int4 q; } u;
  u.h[0] = __float2bfloat16((v0.x-mean)*rstd*w0.x + b0.x);
  u.h[1] = __float2bfloat16((v0.y-mean)*rstd*w0.y + b0.y);
  u.h[2] = __float2bfloat16((v0.z-mean)*rstd*w0.z + b0.z);
  u.h[3] = __float2bfloat16((v0.w-mean)*rstd*w0.w + b0.w);
  u.h[4] = __float2bfloat16((v1.x-mean)*rstd*w1.x + b1.x);
  u.h[5] = __float2bfloat16((v1.y-mean)*rstd*w1.y + b1.y);
  u.h[6] = __float2bfloat16((v1.z-mean)*rstd*w1.z + b1.z);
  u.h[7] = __float2bfloat16((v1.w-mean)*rstd*w1.w + b1.w);
  *(int4*)(outp + (size_t)r*DIMM + lane*8) = u.q;
}

#define M_QKV  0
#define M_PROJ 1
#define M_MLP1 2
#define M_MLP2 3

// ---------------- 2-phase 128x128 GEMM (kept for PROJ: N=512, 512 blocks) ------------
template<int MODE, int K>
__global__ __launch_bounds__(256) void gemm_bt(const bf16* __restrict__ A,
    const bf16* __restrict__ Wt, const float* __restrict__ bias,
    bf16* __restrict__ out_b, float* __restrict__ out_f, const float* __restrict__ skip)
{
  __shared__ bf16 lsA[2][128*32];
  __shared__ bf16 lsB[2][128*32];
  const int tid = threadIdx.x, wave = tid >> 6, lane = tid & 63;
  const int lrow = lane & 15, lgrp = lane >> 4;
  const int m0 = blockIdx.x * 128, n0 = blockIdx.y * 128;
  const int wr = (wave >> 1) * 64, wc = (wave & 1) * 64;

  f32x4 acc[4][4] = {};

  const bf16* Abase = A  + (size_t)m0 * K;
  const bf16* Bbase = Wt + (size_t)n0 * K;
  const int srow = tid >> 2;
  const int scol = (tid & 3) * 8;

  #define STAGE(kt, bf) { \
    gl_lds16(Abase + (size_t)(srow)      * K + (kt) + scol, lsA[bf] + wave*512); \
    gl_lds16(Abase + (size_t)(srow + 64) * K + (kt) + scol, lsA[bf] + 2048 + wave*512); \
    gl_lds16(Bbase + (size_t)(srow)      * K + (kt) + scol, lsB[bf] + wave*512); \
    gl_lds16(Bbase + (size_t)(srow + 64) * K + (kt) + scol, lsB[bf] + 2048 + wave*512); \
  }

  STAGE(0, 0);
  __syncthreads();
  int cur = 0;
  for (int kt = 0; kt < K; kt += 32){
    if (kt + 32 < K) STAGE(kt + 32, cur ^ 1);
    bf16x8 af[4], bfv[4];
    #pragma unroll
    for (int i = 0; i < 4; i++){
      af[i]  = *(const bf16x8*)(lsA[cur] + (wr + i*16 + lrow)*32 + lgrp*8);
      bfv[i] = *(const bf16x8*)(lsB[cur] + (wc + i*16 + lrow)*32 + lgrp*8);
    }
    #pragma unroll
    for (int i = 0; i < 4; i++)
      #pragma unroll
      for (int j = 0; j < 4; j++)
        acc[i][j] = __builtin_amdgcn_mfma_f32_16x16x32_bf16(af[i], bfv[j], acc[i][j], 0, 0, 0);
    __syncthreads();
    cur ^= 1;
  }
  #undef STAGE

  #pragma unroll
  for (int i = 0; i < 4; i++){
    #pragma unroll
    for (int j = 0; j < 4; j++){
      const int col   = n0 + wc + j*16 + lrow;
      const int row_b = m0 + wr + i*16 + lgrp*4;
      const float bv = bias[col];
      #pragma unroll
      for (int rr = 0; rr < 4; rr++){
        const int row = row_b + rr;
        float v = acc[i][j][rr] + bv;
        if constexpr (MODE == M_PROJ){
          const int o = remap_row(row);
          out_f[(size_t)o*DIMM + col] = v + skip[(size_t)o*DIMM + col];
        } else {
          out_f[(size_t)row*DIMM + col] = v; // unused modes
        }
      }
    }
  }
}

// ---------------- 8-phase 256x256 GEMM (T3+T4+T5; linear LDS, T2 next) ---------------
// BM=BN=256, BK=64, 512 thr = 8 waves (2M x 4N), per-wave out 128x64.
// LDS ring: As[2][256][64], Bs[2][256][64] = 128 KiB (dynamic).
// LIVENESS (R3/R4 bug root cause): LDA(0) reads rows {0-63, 128-191} (wm=0/1),
// LDA(1) reads rows {64-127, 192-255} -> BOTH A half-tiles live until ph3's
// lgkmcnt(0). B: per-wave rows wn*64..+63, NH=0 read ph1, NH=1 read ph2 ->
// B0,B1 dead after ph2. Therefore staging into slot s must be:
//   ph1: K(t+1).A1 -> slot sx (other slot, always safe)
//   ph2: NOTHING (staging A0 here was the R3/R4 deterministic corruption)
//   ph3: K(t+2).B0  (B0 dead after ph2's LGKM0, all waves past ph2 barrier)
//   ph4: K(t+2).A0 + K(t+2).B1 (A0 dead after ph3's LGKM0 + ph3 barrier)
// vmcnt ledger: entry outstanding 6 = K(t+1).{B0,A0,B1}; +2(ph1)+2(ph3)+4(ph4)
// = 14; vmcnt(6) retires oldest 8 = K(t+1) complete. vmcnt(0) at t==NT-2.
// Prologue order-insensitive: K0 staged, vmcnt(0) drain, barrier, K1 group.
__device__ __forceinline__ void stage_ht(const bf16* __restrict__ P, int Kdim,
                                         int grow0, bf16* lbase, int tid, int kt){
  const int r = tid >> 3, c = (tid & 7) * 8;
  const bf16* g = P + (size_t)(grow0 + r) * Kdim + kt * 64 + c;
  bf16* l = lbase + r * 64 + c;           // lds dest = wave base + lane*16B (m104-safe)
  gl_lds16(g, l);
  gl_lds16(g + (size_t)64 * Kdim, l + 4096);
}

template<int MODE, int K>
__global__ __launch_bounds__(512, 2) void gemm8_bt(const bf16* __restrict__ A,
    const bf16* __restrict__ Wt, const float* __restrict__ bias,
    bf16* __restrict__ out_b, float* __restrict__ out_f)
{
  constexpr int NT = K / 64;
  extern __shared__ bf16 lds[];
  bf16* As = lds;            // [2][256][64]
  bf16* Bs = lds + 32768;    // [2][256][64]
  const int tid = threadIdx.x;
  const int ln = tid & 63, wv = tid >> 6;
  const int lrow = ln & 15, lgrp = ln >> 4;
  const int wm = wv >> 2, wn = wv & 3;
  const int m0 = blockIdx.x * 256, n0 = blockIdx.y * 256;

  f32x4 acc[8][4] = {};
  bf16x8 aA[4][2], bB0[2][2], bB1[2][2];

  #define LDA(MH) { _Pragma("unroll") for (int mf = 0; mf < 4; mf++) \
    _Pragma("unroll") for (int ks = 0; ks < 2; ks++) \
      aA[mf][ks] = *(const bf16x8*)(As + s*16384 + (wm*128 + (MH)*64 + mf*16 + lrow)*64 + ks*32 + lgrp*8); }
  #define LDB(DST, NH) { _Pragma("unroll") for (int nf = 0; nf < 2; nf++) \
    _Pragma("unroll") for (int ks = 0; ks < 2; ks++) \
      DST[nf][ks] = *(const bf16x8*)(Bs + s*16384 + (wn*64 + (NH)*32 + nf*16 + lrow)*64 + ks*32 + lgrp*8); }
  #define QUAD(BARR, IM0, JN0) { _Pragma("unroll") for (int ks = 0; ks < 2; ks++) \
    _Pragma("unroll") for (int mf = 0; mf < 4; mf++) \
      _Pragma("unroll") for (int nf = 0; nf < 2; nf++) \
        acc[(IM0)+mf][(JN0)+nf] = __builtin_amdgcn_mfma_f32_16x16x32_bf16(aA[mf][ks], BARR[nf][ks], acc[(IM0)+mf][(JN0)+nf], 0, 0, 0); }
  #define SBAR() { __builtin_amdgcn_sched_barrier(0); __builtin_amdgcn_s_barrier(); __builtin_amdgcn_sched_barrier(0); }
  #define LGKM0() { asm volatile("s_waitcnt lgkmcnt(0)" ::: "memory"); __builtin_amdgcn_sched_barrier(0); }

  // ---- prologue (order-insensitive): K0 all 4 half-tiles, drain, barrier
  stage_ht(A,  K, m0,       As,        tid, 0);
  stage_ht(Wt, K, n0,       Bs,        tid, 0);
  stage_ht(Wt, K, n0 + 128, Bs + 8192, tid, 0);
  stage_ht(A,  K, m0 + 128, As + 8192, tid, 0);
  asm volatile("s_waitcnt vmcnt(0)" ::: "memory");
  SBAR();
  // K1.{B0,A0,B1} in flight (internal order irrelevant: retired as a group)
  stage_ht(Wt, K, n0,       Bs + 16384,        tid, 1);
  stage_ht(A,  K, m0,       As + 16384,        tid, 1);
  stage_ht(Wt, K, n0 + 128, Bs + 16384 + 8192, tid, 1);

  for (int t = 0; t < NT; ++t){
    const int s = t & 1;
    const int sx = s ^ 1;
    // ---- phase 1: quad(0,0); stage K(t+1).A1 -> slot sx (not read this iter)
    LDA(0); LDB(bB0, 0);
    if (t + 1 < NT) stage_ht(A, K, m0 + 128, As + sx*16384 + 8192, tid, t + 1);
    SBAR(); LGKM0();
    __builtin_amdgcn_s_setprio(1); QUAD(bB0, 0, 0); __builtin_amdgcn_s_setprio(0);
    SBAR();
    // ---- phase 2: quad(0,1); NO stage (A0 rows 64-127 still live for ph3's LDA(1))
    LDB(bB1, 1);
    SBAR(); LGKM0();
    __builtin_amdgcn_s_setprio(1); QUAD(bB1, 0, 2); __builtin_amdgcn_s_setprio(0);
    SBAR();
    // ---- phase 3: quad(1,1); stage K(t+2).B0 -> slot s (B0 dead after ph2)
    LDA(1);
    if (t + 2 < NT) stage_ht(Wt, K, n0, Bs + s*16384, tid, t + 2);
    SBAR(); LGKM0();
    __builtin_amdgcn_s_setprio(1); QUAD(bB1, 4, 2); __builtin_amdgcn_s_setprio(0);
    SBAR();
    // ---- phase 4: quad(1,0); stage K(t+2).{A0,B1} -> slot s (A0 dead after ph3)
    if (t + 2 < NT){
      stage_ht(A,  K, m0,       As + s*16384,        tid, t + 2);
      stage_ht(Wt, K, n0 + 128, Bs + s*16384 + 8192, tid, t + 2);
    }
    SBAR();
    __builtin_amdgcn_s_setprio(1); QUAD(bB0, 4, 0); __builtin_amdgcn_s_setprio(0);
    if (t == NT - 2)      { asm volatile("s_waitcnt vmcnt(0)" ::: "memory"); }
    else if (t < NT - 2)  { asm volatile("s_waitcnt vmcnt(6)" ::: "memory"); }
    SBAR();
  }
  #undef LDA
  #undef LDB
  #undef QUAD
  #undef SBAR
  #undef LGKM0

  // ---- epilogue: row = m0+wm*128+(im>>2)*64+(im&3)*16+lgrp*4+rr ; col = n0+wn*64+(jn>>1)*32+(jn&1)*16+lrow
  #pragma unroll
  for (int im = 0; im < 8; im++){
    #pragma unroll
    for (int jn = 0; jn < 4; jn++){
      const int col = n0 + wn*64 + (jn >> 1)*32 + (jn & 1)*16 + lrow;
      const int row_b = m0 + wm*128 + (im >> 2)*64 + (im & 3)*16 + lgrp*4;
      const float bv = bias[col];
      #pragma unroll
      for (int rr = 0; rr < 4; rr++){
        const int row = row_b + rr;
        float v = acc[im][jn][rr] + bv;
        if constexpr (MODE == M_QKV){
          const int t = col >> 9, rem = col & 511;
          const int head = rem >> 5, hd = rem & 31;
          const int win = row >> 6, l = row & 63;
          out_b[(size_t)t * (TOK*DIMM) + ((size_t)(win*NHEAD + head)*WLEN + l)*HDIM + hd]
              = __float2bfloat16(v);
        } else if constexpr (MODE == M_MLP1){
          const float u = 1.5957691216057308f * (v + 0.044715f*v*v*v);
          const float g = v * (1.0f / (1.0f + __expf(-u)));
          out_b[(size_t)row*HID + col] = __float2bfloat16(g);
        } else { // M_MLP2
          out_f[(size_t)row*DIMM + col] = 2.f * v;
        }
      }
    }
  }
}

// ---------------- windowed attention: one wave per (window, head) --------------------
__global__ __launch_bounds__(256) void attn_kernel(const bf16* __restrict__ qkv,
    const float* __restrict__ rpb, bf16* __restrict__ outp)
{
  __shared__ bf16 Pl[4][64][72];
  const int wave = threadIdx.x >> 6, lane = threadIdx.x & 63;
  const int lrow = lane & 15, lgrp = lane >> 4;
  const int wh = blockIdx.x * 4 + wave;
  const int win = wh >> 4, head = wh & 15;
  const bf16* qb = qkv + (size_t)wh * (WLEN*HDIM);
  const bf16* kb = qb + (size_t)TOK * DIMM;
  const bf16* vb = kb + (size_t)TOK * DIMM;

  bf16x8 aq[4], ak[4];
  #pragma unroll
  for (int i = 0; i < 4; i++){
    aq[i] = *(const bf16x8*)(qb + (i*16 + lrow)*HDIM + lgrp*8);
    ak[i] = *(const bf16x8*)(kb + (i*16 + lrow)*HDIM + lgrp*8);
  }
  f32x4 s[4][4] = {};
  #pragma unroll
  for (int i = 0; i < 4; i++)
    #pragma unroll
    for (int j = 0; j < 4; j++)
      s[i][j] = __builtin_amdgcn_mfma_f32_16x16x32_bf16(aq[i], ak[j], s[i][j], 0, 0, 0);

  #pragma unroll
  for (int i = 0; i < 4; i++){
    #pragma unroll
    for (int rr = 0; rr < 4; rr++){
      const int srow = i*16 + lgrp*4 + rr;
      const int rq = region_of(win, srow);
      float vals[4]; float mx = -1e30f;
      #pragma unroll
      for (int j = 0; j < 4; j++){
        const int scol = j*16 + lrow;
        const int idx = ((srow>>3) - (scol>>3) + 7)*15 + ((srow&7) - (scol&7) + 7);
        float v = s[i][j][rr]*SCL + rpb[idx*NHEAD + head];
        if (region_of(win, scol) != rq) v -= 100.f;
        vals[j] = v; mx = fmaxf(mx, v);
      }
      mx = fmaxf(mx, __shfl_xor(mx, 1));
      mx = fmaxf(mx, __shfl_xor(mx, 2));
      mx = fmaxf(mx, __shfl_xor(mx, 4));
      mx = fmaxf(mx, __shfl_xor(mx, 8));
      float sum = 0.f;
      #pragma unroll
      for (int j = 0; j < 4; j++){ vals[j] = __expf(vals[j] - mx); sum += vals[j]; }
      sum += __shfl_xor(sum, 1); sum += __shfl_xor(sum, 2);
      sum += __shfl_xor(sum, 4); sum += __shfl_xor(sum, 8);
      const float rs = 1.f / sum;
      #pragma unroll
      for (int j = 0; j < 4; j++)
        Pl[wave][srow][j*16 + lrow] = __float2bfloat16(vals[j] * rs);
    }
  }

  f32x4 o[4][2] = {};
  const __bf16* vraw = (const __bf16*)vb;
  #pragma unroll
  for (int st = 0; st < 2; st++){
    bf16x8 pa[4];
    #pragma unroll
    for (int i = 0; i < 4; i++)
      pa[i] = *(const bf16x8*)(&Pl[wave][i*16 + lrow][st*32 + lgrp*8]);
    bf16x8 bv[2];
    #pragma unroll
    for (int j = 0; j < 2; j++){
      #pragma unroll
      for (int jj = 0; jj < 8; jj++)
        bv[j][jj] = vraw[(size_t)(st*32 + lgrp*8 + jj)*HDIM + j*16 + lrow];
    }
    #pragma unroll
    for (int i = 0; i < 4; i++)
      #pragma unroll
      for (int j = 0; j < 2; j++)
        o[i][j] = __builtin_amdgcn_mfma_f32_16x16x32_bf16(pa[i], bv[j], o[i][j], 0, 0, 0);
  }
  bf16* orow = outp + (size_t)win * WLEN * DIMM + head * HDIM;
  #pragma unroll
  for (int i = 0; i < 4; i++)
    #pragma unroll
    for (int j = 0; j < 2; j++)
      #pragma unroll
      for (int rr = 0; rr < 4; rr++){
        const int l = i*16 + lgrp*4 + rr;
        orow[(size_t)l * DIMM + j*16 + lrow] = __float2bfloat16(o[i][j][rr]);
      }
}

// ---------------- host launch --------------------------------------------------------
extern "C" void kernel_launch(void* const* d_in, const int* in_sizes, int n_in,
                              void* d_out, int out_size, void* d_ws, size_t ws_size,
                              hipStream_t stream) {
  const float* x     = (const float*)d_in[0];
  const float* ln1w  = (const float*)d_in[1];
  const float* ln1b  = (const float*)d_in[2];
  const float* ln2w  = (const float*)d_in[3];
  const float* ln2b  = (const float*)d_in[4];
  const float* qkvw  = (const float*)d_in[5];
  const float* qkvbi = (const float*)d_in[6];
  const float* projw = (const float*)d_in[7];
  const float* projb = (const float*)d_in[8];
  const float* rpb   = (const float*)d_in[9];
  const float* m1w   = (const float*)d_in[10];
  const float* m1b   = (const float*)d_in[11];
  const float* m2w   = (const float*)d_in[12];
  const float* m2b   = (const float*)d_in[13];

  bf16* wqkv  = (bf16*)d_ws;                 // 786432
  bf16* wproj = wqkv + 786432;               // 262144
  bf16* wm1   = wproj + 262144;              // 1048576
  bf16* wm2   = wm1 + 1048576;               // 1048576
  bf16* xw    = wm2 + 1048576;               // 8388608  (LN1 out, window-ordered)
  float* hbuf = (float*)(xw + 8388608);      // 8388608 f32 (attn branch + residual)
  bf16* qkvb  = (bf16*)(hbuf + 8388608);     // 3*8388608 (q,k,v)
  bf16* attno = qkvb + 3*(size_t)8388608;    // 8388608
  bf16* m1buf = qkvb;                        // reuse qkv+attno region
  bf16* h2    = xw;                          // reuse xw (LN2 out)

  hipFuncSetAttribute((const void*)&gemm8_bt<M_QKV, 512>,
                      hipFuncAttributeMaxDynamicSharedMemorySize, 131072);
  hipFuncSetAttribute((const void*)&gemm8_bt<M_MLP1, 512>,
                      hipFuncAttributeMaxDynamicSharedMemorySize, 131072);
  hipFuncSetAttribute((const void*)&gemm8_bt<M_MLP2, 2048>,
                      hipFuncAttributeMaxDynamicSharedMemorySize, 131072);

  convert_w<<<3072, 256, 0, stream>>>(qkvw, projw, m1w, m2w, wqkv);
  ln_kernel<true><<<4096, 256, 0, stream>>>(x, ln1w, ln1b, xw);
  { dim3 g(TOK/256, 1536/256);
    gemm8_bt<M_QKV, 512><<<g, 512, 131072, stream>>>(xw, wqkv, qkvbi, qkvb, nullptr); }
  attn_kernel<<<1024, 256, 0, stream>>>(qkvb, rpb, attno);
  { dim3 g(TOK/128, 512/128);
    gemm_bt<M_PROJ, 512><<<g, 256, 0, stream>>>(attno, wproj, projb, nullptr, hbuf, x); }
  ln_kernel<false><<<4096, 256, 0, stream>>>(hbuf, ln2w, ln2b, h2);
  { dim3 g(TOK/256, 2048/256);
    gemm8_bt<M_MLP1, 512><<<g, 512, 131072, stream>>>(h2, wm1, m1b, m1buf, nullptr); }
  { dim3 g(TOK/256, 512/256);
    gemm8_bt<M_MLP2, 2048><<<g, 512, 131072, stream>>>(m1buf, wm2, m2b, nullptr, (float*)d_out); }
}

// Round 6
// 229.589 us; speedup vs baseline: 1.1754x; 1.1754x over previous
//
#include <hip/hip_runtime.h>
#include <hip/hip_bf16.h>
#include <stdint.h>

// Problem constants (all static per reference)
#define TOK   16384
#define DIMM  512
#define NHEAD 16
#define HDIM  32
#define HID   2048
#define NWIN  256
#define WLEN  64
#define EPSV  1e-5f
#define SCL   0.17677669529663687f   // 32^-0.5

typedef __hip_bfloat16 bf16;
typedef __attribute__((ext_vector_type(8))) __bf16 bf16x8;
typedef __attribute__((ext_vector_type(4))) float f32x4;

// window-order row r (win*64 + l, shifted coords) -> original token row
__device__ __forceinline__ int remap_row(int r){
  int win = r >> 6, l = r & 63;
  int gh = ((win >> 4) << 3) + (l >> 3);
  int gw = ((win & 15) << 3) + (l & 7);
  int oh = (gh + 4) & 127, ow = (gw + 4) & 127;
  return (oh << 7) + ow;
}

// Swin shift-mask region id (slices: [0,120) [120,124) [124,128) on each axis)
__device__ __forceinline__ int region_of(int win, int l){
  int gh = ((win >> 4) << 3) + (l >> 3);
  int gw = ((win & 15) << 3) + (l & 7);
  int rh = (gh < 120) ? 0 : ((gh < 124) ? 1 : 2);
  int rw = (gw < 120) ? 0 : ((gw < 124) ? 1 : 2);
  return rh * 3 + rw;
}

__device__ __forceinline__ void gl_lds16(const bf16* g, bf16* l){
  __builtin_amdgcn_global_load_lds((const __attribute__((address_space(1))) void*)g,
                                   (__attribute__((address_space(3))) void*)l, 16, 0, 0);
}

// ---------------- weight fp32 -> bf16 convert (4 ranges, contiguous dst) -------------
__global__ __launch_bounds__(256) void convert_w(const float* __restrict__ a,
                                                 const float* __restrict__ b,
                                                 const float* __restrict__ c,
                                                 const float* __restrict__ d,
                                                 bf16* __restrict__ dst){
  int e = (blockIdx.x * 256 + threadIdx.x) * 4;
  float4 v;
  if (e < 786432)        v = *(const float4*)(a + e);
  else if (e < 1048576)  v = *(const float4*)(b + (e - 786432));
  else if (e < 2097152)  v = *(const float4*)(c + (e - 1048576));
  else                   v = *(const float4*)(d + (e - 2097152));
  union { bf16 h[4]; int2 q; } u;
  u.h[0] = __float2bfloat16(v.x); u.h[1] = __float2bfloat16(v.y);
  u.h[2] = __float2bfloat16(v.z); u.h[3] = __float2bfloat16(v.w);
  *(int2*)(dst + e) = u.q;
}

// ---------------- LayerNorm (one wave per row), optional shift+window remap ----------
template<bool REMAP>
__global__ __launch_bounds__(256) void ln_kernel(const float* __restrict__ in,
    const float* __restrict__ w, const float* __restrict__ b, bf16* __restrict__ outp)
{
  const int wave = threadIdx.x >> 6, lane = threadIdx.x & 63;
  const int r = blockIdx.x * 4 + wave;
  const int src = REMAP ? remap_row(r) : r;
  const float4* row = (const float4*)(in + (size_t)src * DIMM);
  float4 v0 = row[lane*2], v1 = row[lane*2 + 1];
  float sm = v0.x+v0.y+v0.z+v0.w + v1.x+v1.y+v1.z+v1.w;
  float sq = v0.x*v0.x+v0.y*v0.y+v0.z*v0.z+v0.w*v0.w
           + v1.x*v1.x+v1.y*v1.y+v1.z*v1.z+v1.w*v1.w;
  #pragma unroll
  for (int off = 1; off < 64; off <<= 1){
    sm += __shfl_xor(sm, off);
    sq += __shfl_xor(sq, off);
  }
  const float mean = sm * (1.f/512.f);
  const float rstd = rsqrtf(sq*(1.f/512.f) - mean*mean + EPSV);
  const float4* wp = (const float4*)w; const float4* bp = (const float4*)b;
  float4 w0 = wp[lane*2], w1 = wp[lane*2+1], b0 = bp[lane*2], b1 = bp[lane*2+1];
  union { bf16 h[8]; int4 q; } u;
  u.h[0] = __float2bfloat16((v0.x-mean)*rstd*w0.x + b0.x);
  u.h[1] = __float2bfloat16((v0.y-mean)*rstd*w0.y + b0.y);
  u.h[2] = __float2bfloat16((v0.z-mean)*rstd*w0.z + b0.z);
  u.h[3] = __float2bfloat16((v0.w-mean)*rstd*w0.w + b0.w);
  u.h[4] = __float2bfloat16((v1.x-mean)*rstd*w1.x + b1.x);
  u.h[5] = __float2bfloat16((v1.y-mean)*rstd*w1.y + b1.y);
  u.h[6] = __float2bfloat16((v1.z-mean)*rstd*w1.z + b1.z);
  u.h[7] = __float2bfloat16((v1.w-mean)*rstd*w1.w + b1.w);
  *(int4*)(outp + (size_t)r*DIMM + lane*8) = u.q;
}

#define M_QKV  0
#define M_PROJ 1
#define M_MLP1 2
#define M_MLP2 3
#define M_PART 4

// ---------------- 2-phase 128x128 GEMM (kept for PROJ: N=512, 512 blocks) ------------
template<int MODE, int K>
__global__ __launch_bounds__(256) void gemm_bt(const bf16* __restrict__ A,
    const bf16* __restrict__ Wt, const float* __restrict__ bias,
    bf16* __restrict__ out_b, float* __restrict__ out_f, const float* __restrict__ skip)
{
  __shared__ bf16 lsA[2][128*32];
  __shared__ bf16 lsB[2][128*32];
  const int tid = threadIdx.x, wave = tid >> 6, lane = tid & 63;
  const int lrow = lane & 15, lgrp = lane >> 4;
  const int m0 = blockIdx.x * 128, n0 = blockIdx.y * 128;
  const int wr = (wave >> 1) * 64, wc = (wave & 1) * 64;

  f32x4 acc[4][4] = {};

  const bf16* Abase = A  + (size_t)m0 * K;
  const bf16* Bbase = Wt + (size_t)n0 * K;
  const int srow = tid >> 2;
  const int scol = (tid & 3) * 8;

  #define STAGE(kt, bf) { \
    gl_lds16(Abase + (size_t)(srow)      * K + (kt) + scol, lsA[bf] + wave*512); \
    gl_lds16(Abase + (size_t)(srow + 64) * K + (kt) + scol, lsA[bf] + 2048 + wave*512); \
    gl_lds16(Bbase + (size_t)(srow)      * K + (kt) + scol, lsB[bf] + wave*512); \
    gl_lds16(Bbase + (size_t)(srow + 64) * K + (kt) + scol, lsB[bf] + 2048 + wave*512); \
  }

  STAGE(0, 0);
  __syncthreads();
  int cur = 0;
  for (int kt = 0; kt < K; kt += 32){
    if (kt + 32 < K) STAGE(kt + 32, cur ^ 1);
    bf16x8 af[4], bfv[4];
    #pragma unroll
    for (int i = 0; i < 4; i++){
      af[i]  = *(const bf16x8*)(lsA[cur] + (wr + i*16 + lrow)*32 + lgrp*8);
      bfv[i] = *(const bf16x8*)(lsB[cur] + (wc + i*16 + lrow)*32 + lgrp*8);
    }
    #pragma unroll
    for (int i = 0; i < 4; i++)
      #pragma unroll
      for (int j = 0; j < 4; j++)
        acc[i][j] = __builtin_amdgcn_mfma_f32_16x16x32_bf16(af[i], bfv[j], acc[i][j], 0, 0, 0);
    __syncthreads();
    cur ^= 1;
  }
  #undef STAGE

  #pragma unroll
  for (int i = 0; i < 4; i++){
    #pragma unroll
    for (int j = 0; j < 4; j++){
      const int col   = n0 + wc + j*16 + lrow;
      const int row_b = m0 + wr + i*16 + lgrp*4;
      const float bv = bias[col];
      #pragma unroll
      for (int rr = 0; rr < 4; rr++){
        const int row = row_b + rr;
        float v = acc[i][j][rr] + bv;
        if constexpr (MODE == M_PROJ){
          const int o = remap_row(row);
          out_f[(size_t)o*DIMM + col] = v + skip[(size_t)o*DIMM + col];
        } else {
          out_f[(size_t)row*DIMM + col] = v; // unused modes
        }
      }
    }
  }
}

// ---------------- 8-phase 256x256 GEMM (T3+T4+T5 + T2 swizzle) -----------------------
// BM=BN=256, BK=64, 512 thr = 8 waves (2M x 4N), per-wave out 128x64.
// LDS ring: As[2][256][64], Bs[2][256][64] = 128 KiB (dynamic).
// LIVENESS (R3/R4 lesson): LDA(0) reads rows {0-63,128-191}, LDA(1) {64-127,
// 192-255} -> both A half-tiles live until ph3. B0,B1 dead after ph2.
//   ph1: K(t+1).A1 -> other slot; ph2: NOTHING; ph3: K(t+2).B0; ph4: K(t+2).{A0,B1}
// vmcnt: entry outstanding 6 = K(t+1).{B0,A0,B1}; vmcnt(6) retires K(t+1); 0 at NT-2.
// T2 SWIZZLE (rule #21 both-sides): logical (row,col) at phys byte
// row*128 + (colbyte ^ ((row&7)<<4)). LDS dest stays LINEAR (gl_lds16), the
// GLOBAL source col is pre-swizzled: chunk = (tid&7)^((tid>>3)&7) (valid for
// both sub-rows: +64 == 0 mod 8); ds_read applies chunk=(ks*4+lgrp)^(lrow&7)
// (all other row terms are multiples of 8). Distribution: 8 lanes per 4-bank
// group = even = b128 floor, conflict-free.
template<int KSTR>
__device__ __forceinline__ void stage_ht(const bf16* __restrict__ P,
                                         int grow0, bf16* lbase, int tid, int kt){
  const int r = tid >> 3;
  const int c = ((tid & 7) ^ (r & 7)) * 8;      // pre-swizzled source column
  const bf16* g = P + (size_t)(grow0 + r) * KSTR + kt * 64 + c;
  bf16* l = lbase + r * 64 + (tid & 7) * 8;     // linear dest (wave base + lane*16B)
  gl_lds16(g, l);
  gl_lds16(g + (size_t)64 * KSTR, l + 4096);
}

template<int MODE, int KEXT, int KSTR = KEXT>
__global__ __launch_bounds__(512, 2) void gemm8_bt(const bf16* __restrict__ A,
    const bf16* __restrict__ Wt, const float* __restrict__ bias,
    bf16* __restrict__ out_b, float* __restrict__ out_f, float* __restrict__ out_f2)
{
  constexpr int NT = KEXT / 64;
  extern __shared__ bf16 lds[];
  bf16* As = lds;            // [2][256][64] swizzled
  bf16* Bs = lds + 32768;    // [2][256][64] swizzled
  const int tid = threadIdx.x;
  const int ln = tid & 63, wv = tid >> 6;
  const int lrow = ln & 15, lgrp = ln >> 4;
  const int swz = lrow & 7;
  const int wm = wv >> 2, wn = wv & 3;
  const int m0 = blockIdx.x * 256, n0 = blockIdx.y * 256;

  if constexpr (MODE == M_PART){          // split-K slab select
    const int z = blockIdx.z;
    A  += z * 1024;
    Wt += z * 1024;
  }

  f32x4 acc[8][4] = {};
  bf16x8 aA[4][2], bB0[2][2], bB1[2][2];

  #define LDA(MH) { _Pragma("unroll") for (int mf = 0; mf < 4; mf++) \
    _Pragma("unroll") for (int ks = 0; ks < 2; ks++) \
      aA[mf][ks] = *(const bf16x8*)(As + s*16384 + (wm*128 + (MH)*64 + mf*16 + lrow)*64 + ((ks*4 + lgrp) ^ swz)*8); }
  #define LDB(DST, NH) { _Pragma("unroll") for (int nf = 0; nf < 2; nf++) \
    _Pragma("unroll") for (int ks = 0; ks < 2; ks++) \
      DST[nf][ks] = *(const bf16x8*)(Bs + s*16384 + (wn*64 + (NH)*32 + nf*16 + lrow)*64 + ((ks*4 + lgrp) ^ swz)*8); }
  #define QUAD(BARR, IM0, JN0) { _Pragma("unroll") for (int ks = 0; ks < 2; ks++) \
    _Pragma("unroll") for (int mf = 0; mf < 4; mf++) \
      _Pragma("unroll") for (int nf = 0; nf < 2; nf++) \
        acc[(IM0)+mf][(JN0)+nf] = __builtin_amdgcn_mfma_f32_16x16x32_bf16(aA[mf][ks], BARR[nf][ks], acc[(IM0)+mf][(JN0)+nf], 0, 0, 0); }
  #define SBAR() { __builtin_amdgcn_sched_barrier(0); __builtin_amdgcn_s_barrier(); __builtin_amdgcn_sched_barrier(0); }
  #define LGKM0() { asm volatile("s_waitcnt lgkmcnt(0)" ::: "memory"); __builtin_amdgcn_sched_barrier(0); }

  // ---- prologue (order-insensitive): K0 all 4 half-tiles, drain, barrier
  stage_ht<KSTR>(A,  m0,       As,        tid, 0);
  stage_ht<KSTR>(Wt, n0,       Bs,        tid, 0);
  stage_ht<KSTR>(Wt, n0 + 128, Bs + 8192, tid, 0);
  stage_ht<KSTR>(A,  m0 + 128, As + 8192, tid, 0);
  asm volatile("s_waitcnt vmcnt(0)" ::: "memory");
  SBAR();
  // K1.{B0,A0,B1} in flight (retired as a group)
  stage_ht<KSTR>(Wt, n0,       Bs + 16384,        tid, 1);
  stage_ht<KSTR>(A,  m0,       As + 16384,        tid, 1);
  stage_ht<KSTR>(Wt, n0 + 128, Bs + 16384 + 8192, tid, 1);

  for (int t = 0; t < NT; ++t){
    const int s = t & 1;
    const int sx = s ^ 1;
    // ---- phase 1: quad(0,0); stage K(t+1).A1 -> slot sx
    LDA(0); LDB(bB0, 0);
    if (t + 1 < NT) stage_ht<KSTR>(A, m0 + 128, As + sx*16384 + 8192, tid, t + 1);
    SBAR(); LGKM0();
    __builtin_amdgcn_s_setprio(1); QUAD(bB0, 0, 0); __builtin_amdgcn_s_setprio(0);
    SBAR();
    // ---- phase 2: quad(0,1); NO stage (A0 rows 64-127 live for ph3's LDA(1))
    LDB(bB1, 1);
    SBAR(); LGKM0();
    __builtin_amdgcn_s_setprio(1); QUAD(bB1, 0, 2); __builtin_amdgcn_s_setprio(0);
    SBAR();
    // ---- phase 3: quad(1,1); stage K(t+2).B0 -> slot s (B0 dead after ph2)
    LDA(1);
    if (t + 2 < NT) stage_ht<KSTR>(Wt, n0, Bs + s*16384, tid, t + 2);
    SBAR(); LGKM0();
    __builtin_amdgcn_s_setprio(1); QUAD(bB1, 4, 2); __builtin_amdgcn_s_setprio(0);
    SBAR();
    // ---- phase 4: quad(1,0); stage K(t+2).{A0,B1} -> slot s (A0 dead after ph3)
    if (t + 2 < NT){
      stage_ht<KSTR>(A,  m0,       As + s*16384,        tid, t + 2);
      stage_ht<KSTR>(Wt, n0 + 128, Bs + s*16384 + 8192, tid, t + 2);
    }
    SBAR();
    __builtin_amdgcn_s_setprio(1); QUAD(bB0, 4, 0); __builtin_amdgcn_s_setprio(0);
    if (t == NT - 2)      { asm volatile("s_waitcnt vmcnt(0)" ::: "memory"); }
    else if (t < NT - 2)  { asm volatile("s_waitcnt vmcnt(6)" ::: "memory"); }
    SBAR();
  }
  #undef LDA
  #undef LDB
  #undef QUAD
  #undef SBAR
  #undef LGKM0

  // ---- epilogue
  float* pdst = nullptr;
  if constexpr (MODE == M_PART) pdst = blockIdx.z ? out_f2 : out_f;
  #pragma unroll
  for (int im = 0; im < 8; im++){
    #pragma unroll
    for (int jn = 0; jn < 4; jn++){
      const int col = n0 + wn*64 + (jn >> 1)*32 + (jn & 1)*16 + lrow;
      const int row_b = m0 + wm*128 + (im >> 2)*64 + (im & 3)*16 + lgrp*4;
      const float bv = (MODE == M_PART) ? 0.f : bias[col];
      #pragma unroll
      for (int rr = 0; rr < 4; rr++){
        const int row = row_b + rr;
        float v = acc[im][jn][rr] + bv;
        if constexpr (MODE == M_QKV){
          const int t = col >> 9, rem = col & 511;
          const int head = rem >> 5, hd = rem & 31;
          const int win = row >> 6, l = row & 63;
          out_b[(size_t)t * (TOK*DIMM) + ((size_t)(win*NHEAD + head)*WLEN + l)*HDIM + hd]
              = __float2bfloat16(v);
        } else if constexpr (MODE == M_MLP1){
          const float u = 1.5957691216057308f * (v + 0.044715f*v*v*v);
          const float g = v * (1.0f / (1.0f + __expf(-u)));
          out_b[(size_t)row*HID + col] = __float2bfloat16(g);
        } else if constexpr (MODE == M_PART){
          pdst[(size_t)row*DIMM + col] = v;     // raw partial (bias in reduce)
        } else { // M_MLP2 (unused now)
          out_f[(size_t)row*DIMM + col] = 2.f * v;
        }
      }
    }
  }
}

// ---------------- MLP2 split-K reduce: d_out = 2*(p0 + p1 + bias) --------------------
__global__ __launch_bounds__(256) void mlp2_reduce(const float* __restrict__ p0,
    float* __restrict__ dout, const float* __restrict__ bias){
  const int i = blockIdx.x * 256 + threadIdx.x;     // float4 index
  const int e = i * 4;
  float4 a = *(const float4*)(p0 + e);
  float4 b = *(const float4*)(dout + e);
  float4 bv = *(const float4*)(bias + (e & 511));
  float4 r;
  r.x = 2.f*(a.x + b.x + bv.x);
  r.y = 2.f*(a.y + b.y + bv.y);
  r.z = 2.f*(a.z + b.z + bv.z);
  r.w = 2.f*(a.w + b.w + bv.w);
  *(float4*)(dout + e) = r;
}

// ---------------- windowed attention: one wave per (window, head) --------------------
__global__ __launch_bounds__(256) void attn_kernel(const bf16* __restrict__ qkv,
    const float* __restrict__ rpb, bf16* __restrict__ outp)
{
  __shared__ bf16 Pl[4][64][72];
  const int wave = threadIdx.x >> 6, lane = threadIdx.x & 63;
  const int lrow = lane & 15, lgrp = lane >> 4;
  const int wh = blockIdx.x * 4 + wave;
  const int win = wh >> 4, head = wh & 15;
  const bf16* qb = qkv + (size_t)wh * (WLEN*HDIM);
  const bf16* kb = qb + (size_t)TOK * DIMM;
  const bf16* vb = kb + (size_t)TOK * DIMM;

  bf16x8 aq[4], ak[4];
  #pragma unroll
  for (int i = 0; i < 4; i++){
    aq[i] = *(const bf16x8*)(qb + (i*16 + lrow)*HDIM + lgrp*8);
    ak[i] = *(const bf16x8*)(kb + (i*16 + lrow)*HDIM + lgrp*8);
  }
  f32x4 s[4][4] = {};
  #pragma unroll
  for (int i = 0; i < 4; i++)
    #pragma unroll
    for (int j = 0; j < 4; j++)
      s[i][j] = __builtin_amdgcn_mfma_f32_16x16x32_bf16(aq[i], ak[j], s[i][j], 0, 0, 0);

  #pragma unroll
  for (int i = 0; i < 4; i++){
    #pragma unroll
    for (int rr = 0; rr < 4; rr++){
      const int srow = i*16 + lgrp*4 + rr;
      const int rq = region_of(win, srow);
      float vals[4]; float mx = -1e30f;
      #pragma unroll
      for (int j = 0; j < 4; j++){
        const int scol = j*16 + lrow;
        const int idx = ((srow>>3) - (scol>>3) + 7)*15 + ((srow&7) - (scol&7) + 7);
        float v = s[i][j][rr]*SCL + rpb[idx*NHEAD + head];
        if (region_of(win, scol) != rq) v -= 100.f;
        vals[j] = v; mx = fmaxf(mx, v);
      }
      mx = fmaxf(mx, __shfl_xor(mx, 1));
      mx = fmaxf(mx, __shfl_xor(mx, 2));
      mx = fmaxf(mx, __shfl_xor(mx, 4));
      mx = fmaxf(mx, __shfl_xor(mx, 8));
      float sum = 0.f;
      #pragma unroll
      for (int j = 0; j < 4; j++){ vals[j] = __expf(vals[j] - mx); sum += vals[j]; }
      sum += __shfl_xor(sum, 1); sum += __shfl_xor(sum, 2);
      sum += __shfl_xor(sum, 4); sum += __shfl_xor(sum, 8);
      const float rs = 1.f / sum;
      #pragma unroll
      for (int j = 0; j < 4; j++)
        Pl[wave][srow][j*16 + lrow] = __float2bfloat16(vals[j] * rs);
    }
  }

  f32x4 o[4][2] = {};
  const __bf16* vraw = (const __bf16*)vb;
  #pragma unroll
  for (int st = 0; st < 2; st++){
    bf16x8 pa[4];
    #pragma unroll
    for (int i = 0; i < 4; i++)
      pa[i] = *(const bf16x8*)(&Pl[wave][i*16 + lrow][st*32 + lgrp*8]);
    bf16x8 bv[2];
    #pragma unroll
    for (int j = 0; j < 2; j++){
      #pragma unroll
      for (int jj = 0; jj < 8; jj++)
        bv[j][jj] = vraw[(size_t)(st*32 + lgrp*8 + jj)*HDIM + j*16 + lrow];
    }
    #pragma unroll
    for (int i = 0; i < 4; i++)
      #pragma unroll
      for (int j = 0; j < 2; j++)
        o[i][j] = __builtin_amdgcn_mfma_f32_16x16x32_bf16(pa[i], bv[j], o[i][j], 0, 0, 0);
  }
  bf16* orow = outp + (size_t)win * WLEN * DIMM + head * HDIM;
  #pragma unroll
  for (int i = 0; i < 4; i++)
    #pragma unroll
    for (int j = 0; j < 2; j++)
      #pragma unroll
      for (int rr = 0; rr < 4; rr++){
        const int l = i*16 + lgrp*4 + rr;
        orow[(size_t)l * DIMM + j*16 + lrow] = __float2bfloat16(o[i][j][rr]);
      }
}

// ---------------- host launch --------------------------------------------------------
extern "C" void kernel_launch(void* const* d_in, const int* in_sizes, int n_in,
                              void* d_out, int out_size, void* d_ws, size_t ws_size,
                              hipStream_t stream) {
  const float* x     = (const float*)d_in[0];
  const float* ln1w  = (const float*)d_in[1];
  const float* ln1b  = (const float*)d_in[2];
  const float* ln2w  = (const float*)d_in[3];
  const float* ln2b  = (const float*)d_in[4];
  const float* qkvw  = (const float*)d_in[5];
  const float* qkvbi = (const float*)d_in[6];
  const float* projw = (const float*)d_in[7];
  const float* projb = (const float*)d_in[8];
  const float* rpb   = (const float*)d_in[9];
  const float* m1w   = (const float*)d_in[10];
  const float* m1b   = (const float*)d_in[11];
  const float* m2w   = (const float*)d_in[12];
  const float* m2b   = (const float*)d_in[13];

  bf16* wqkv  = (bf16*)d_ws;                 // 786432
  bf16* wproj = wqkv + 786432;               // 262144
  bf16* wm1   = wproj + 262144;              // 1048576
  bf16* wm2   = wm1 + 1048576;               // 1048576
  bf16* xw    = wm2 + 1048576;               // 8388608  (LN1 out, window-ordered)
  float* hbuf = (float*)(xw + 8388608);      // 8388608 f32 (attn residual; later MLP2 partial0)
  bf16* qkvb  = (bf16*)(hbuf + 8388608);     // 3*8388608 (q,k,v)
  bf16* attno = qkvb + 3*(size_t)8388608;    // 8388608
  bf16* m1buf = qkvb;                        // reuse qkv+attno region
  bf16* h2    = xw;                          // reuse xw (LN2 out)

  hipFuncSetAttribute((const void*)&gemm8_bt<M_QKV, 512>,
                      hipFuncAttributeMaxDynamicSharedMemorySize, 131072);
  hipFuncSetAttribute((const void*)&gemm8_bt<M_MLP1, 512>,
                      hipFuncAttributeMaxDynamicSharedMemorySize, 131072);
  hipFuncSetAttribute((const void*)&gemm8_bt<M_PART, 1024, 2048>,
                      hipFuncAttributeMaxDynamicSharedMemorySize, 131072);

  convert_w<<<3072, 256, 0, stream>>>(qkvw, projw, m1w, m2w, wqkv);
  ln_kernel<true><<<4096, 256, 0, stream>>>(x, ln1w, ln1b, xw);
  { dim3 g(TOK/256, 1536/256);
    gemm8_bt<M_QKV, 512><<<g, 512, 131072, stream>>>(xw, wqkv, qkvbi, qkvb, nullptr, nullptr); }
  attn_kernel<<<1024, 256, 0, stream>>>(qkvb, rpb, attno);
  { dim3 g(TOK/128, 512/128);
    gemm_bt<M_PROJ, 512><<<g, 256, 0, stream>>>(attno, wproj, projb, nullptr, hbuf, x); }
  ln_kernel<false><<<4096, 256, 0, stream>>>(hbuf, ln2w, ln2b, h2);
  { dim3 g(TOK/256, 2048/256);
    gemm8_bt<M_MLP1, 512><<<g, 512, 131072, stream>>>(h2, wm1, m1b, m1buf, nullptr, nullptr); }
  // MLP2 split-K=2: slab0 -> hbuf (dead after LN2), slab1 -> d_out (raw partial)
  { dim3 g(TOK/256, 512/256, 2);
    gemm8_bt<M_PART, 1024, 2048><<<g, 512, 131072, stream>>>(m1buf, wm2, m2b, nullptr,
                                                             hbuf, (float*)d_out); }
  mlp2_reduce<<<8388608/4/256, 256, 0, stream>>>(hbuf, (float*)d_out, m2b);
}

// Round 7
// 222.595 us; speedup vs baseline: 1.2123x; 1.0314x over previous
//
#include <hip/hip_runtime.h>
#include <hip/hip_bf16.h>
#include <stdint.h>

// Problem constants (all static per reference)
#define TOK   16384
#define DIMM  512
#define NHEAD 16
#define HDIM  32
#define HID   2048
#define NWIN  256
#define WLEN  64
#define EPSV  1e-5f
#define SCL   0.17677669529663687f   // 32^-0.5

typedef __hip_bfloat16 bf16;
typedef __attribute__((ext_vector_type(8))) __bf16 bf16x8;
typedef __attribute__((ext_vector_type(4))) float f32x4;

// window-order row r (win*64 + l, shifted coords) -> original token row
__device__ __forceinline__ int remap_row(int r){
  int win = r >> 6, l = r & 63;
  int gh = ((win >> 4) << 3) + (l >> 3);
  int gw = ((win & 15) << 3) + (l & 7);
  int oh = (gh + 4) & 127, ow = (gw + 4) & 127;
  return (oh << 7) + ow;
}

// Swin shift-mask region id (slices: [0,120) [120,124) [124,128) on each axis)
__device__ __forceinline__ int region_of(int win, int l){
  int gh = ((win >> 4) << 3) + (l >> 3);
  int gw = ((win & 15) << 3) + (l & 7);
  int rh = (gh < 120) ? 0 : ((gh < 124) ? 1 : 2);
  int rw = (gw < 120) ? 0 : ((gw < 124) ? 1 : 2);
  return rh * 3 + rw;
}

__device__ __forceinline__ void gl_lds16(const bf16* g, bf16* l){
  __builtin_amdgcn_global_load_lds((const __attribute__((address_space(1))) void*)g,
                                   (__attribute__((address_space(3))) void*)l, 16, 0, 0);
}

// ---------------- weight fp32 -> bf16 convert (4 ranges, contiguous dst) -------------
__global__ __launch_bounds__(256) void convert_w(const float* __restrict__ a,
                                                 const float* __restrict__ b,
                                                 const float* __restrict__ c,
                                                 const float* __restrict__ d,
                                                 bf16* __restrict__ dst){
  int e = (blockIdx.x * 256 + threadIdx.x) * 4;
  float4 v;
  if (e < 786432)        v = *(const float4*)(a + e);
  else if (e < 1048576)  v = *(const float4*)(b + (e - 786432));
  else if (e < 2097152)  v = *(const float4*)(c + (e - 1048576));
  else                   v = *(const float4*)(d + (e - 2097152));
  union { bf16 h[4]; int2 q; } u;
  u.h[0] = __float2bfloat16(v.x); u.h[1] = __float2bfloat16(v.y);
  u.h[2] = __float2bfloat16(v.z); u.h[3] = __float2bfloat16(v.w);
  *(int2*)(dst + e) = u.q;
}

// ---------------- LayerNorm (one wave per row), optional shift+window remap ----------
template<bool REMAP>
__global__ __launch_bounds__(256) void ln_kernel(const float* __restrict__ in,
    const float* __restrict__ w, const float* __restrict__ b, bf16* __restrict__ outp)
{
  const int wave = threadIdx.x >> 6, lane = threadIdx.x & 63;
  const int r = blockIdx.x * 4 + wave;
  const int src = REMAP ? remap_row(r) : r;
  const float4* row = (const float4*)(in + (size_t)src * DIMM);
  float4 v0 = row[lane*2], v1 = row[lane*2 + 1];
  float sm = v0.x+v0.y+v0.z+v0.w + v1.x+v1.y+v1.z+v1.w;
  float sq = v0.x*v0.x+v0.y*v0.y+v0.z*v0.z+v0.w*v0.w
           + v1.x*v1.x+v1.y*v1.y+v1.z*v1.z+v1.w*v1.w;
  #pragma unroll
  for (int off = 1; off < 64; off <<= 1){
    sm += __shfl_xor(sm, off);
    sq += __shfl_xor(sq, off);
  }
  const float mean = sm * (1.f/512.f);
  const float rstd = rsqrtf(sq*(1.f/512.f) - mean*mean + EPSV);
  const float4* wp = (const float4*)w; const float4* bp = (const float4*)b;
  float4 w0 = wp[lane*2], w1 = wp[lane*2+1], b0 = bp[lane*2], b1 = bp[lane*2+1];
  union { bf16 h[8]; int4 q; } u;
  u.h[0] = __float2bfloat16((v0.x-mean)*rstd*w0.x + b0.x);
  u.h[1] = __float2bfloat16((v0.y-mean)*rstd*w0.y + b0.y);
  u.h[2] = __float2bfloat16((v0.z-mean)*rstd*w0.z + b0.z);
  u.h[3] = __float2bfloat16((v0.w-mean)*rstd*w0.w + b0.w);
  u.h[4] = __float2bfloat16((v1.x-mean)*rstd*w1.x + b1.x);
  u.h[5] = __float2bfloat16((v1.y-mean)*rstd*w1.y + b1.y);
  u.h[6] = __float2bfloat16((v1.z-mean)*rstd*w1.z + b1.z);
  u.h[7] = __float2bfloat16((v1.w-mean)*rstd*w1.w + b1.w);
  *(int4*)(outp + (size_t)r*DIMM + lane*8) = u.q;
}

#define M_QKV  0
#define M_PROJ 1
#define M_MLP1 2
#define M_MLP2 3
#define M_PART 4

// ---------------- 2-phase 128x128 GEMM (kept for PROJ: N=512, 512 blocks) ------------
template<int MODE, int K>
__global__ __launch_bounds__(256) void gemm_bt(const bf16* __restrict__ A,
    const bf16* __restrict__ Wt, const float* __restrict__ bias,
    bf16* __restrict__ out_b, float* __restrict__ out_f, const float* __restrict__ skip)
{
  __shared__ bf16 lsA[2][128*32];
  __shared__ bf16 lsB[2][128*32];
  const int tid = threadIdx.x, wave = tid >> 6, lane = tid & 63;
  const int lrow = lane & 15, lgrp = lane >> 4;
  const int m0 = blockIdx.x * 128, n0 = blockIdx.y * 128;
  const int wr = (wave >> 1) * 64, wc = (wave & 1) * 64;

  f32x4 acc[4][4] = {};

  const bf16* Abase = A  + (size_t)m0 * K;
  const bf16* Bbase = Wt + (size_t)n0 * K;
  const int srow = tid >> 2;
  const int scol = (tid & 3) * 8;

  #define STAGE(kt, bf) { \
    gl_lds16(Abase + (size_t)(srow)      * K + (kt) + scol, lsA[bf] + wave*512); \
    gl_lds16(Abase + (size_t)(srow + 64) * K + (kt) + scol, lsA[bf] + 2048 + wave*512); \
    gl_lds16(Bbase + (size_t)(srow)      * K + (kt) + scol, lsB[bf] + wave*512); \
    gl_lds16(Bbase + (size_t)(srow + 64) * K + (kt) + scol, lsB[bf] + 2048 + wave*512); \
  }

  STAGE(0, 0);
  __syncthreads();
  int cur = 0;
  for (int kt = 0; kt < K; kt += 32){
    if (kt + 32 < K) STAGE(kt + 32, cur ^ 1);
    bf16x8 af[4], bfv[4];
    #pragma unroll
    for (int i = 0; i < 4; i++){
      af[i]  = *(const bf16x8*)(lsA[cur] + (wr + i*16 + lrow)*32 + lgrp*8);
      bfv[i] = *(const bf16x8*)(lsB[cur] + (wc + i*16 + lrow)*32 + lgrp*8);
    }
    #pragma unroll
    for (int i = 0; i < 4; i++)
      #pragma unroll
      for (int j = 0; j < 4; j++)
        acc[i][j] = __builtin_amdgcn_mfma_f32_16x16x32_bf16(af[i], bfv[j], acc[i][j], 0, 0, 0);
    __syncthreads();
    cur ^= 1;
  }
  #undef STAGE

  #pragma unroll
  for (int i = 0; i < 4; i++){
    #pragma unroll
    for (int j = 0; j < 4; j++){
      const int col   = n0 + wc + j*16 + lrow;
      const int row_b = m0 + wr + i*16 + lgrp*4;
      const float bv = bias[col];
      #pragma unroll
      for (int rr = 0; rr < 4; rr++){
        const int row = row_b + rr;
        float v = acc[i][j][rr] + bv;
        if constexpr (MODE == M_PROJ){
          const int o = remap_row(row);
          out_f[(size_t)o*DIMM + col] = v + skip[(size_t)o*DIMM + col];
        } else {
          out_f[(size_t)row*DIMM + col] = v; // unused modes
        }
      }
    }
  }
}

// ---------------- 8-phase 256x256 GEMM (T3+T4+T5 + T2 swizzle) -----------------------
// BM=BN=256, BK=64, 512 thr = 8 waves (2M x 4N), per-wave out 128x64.
// LDS ring: As[2][256][64], Bs[2][256][64] = 128 KiB (dynamic).
// LIVENESS: LDA(0) reads rows {0-63,128-191}, LDA(1) {64-127,192-255} -> both
// A half-tiles live until ph3's lgkm. B0,B1 dead after ph2.
//   ph1: K(t+1).A1 -> other slot; ph2: NOTHING; ph3: K(t+2).B0; ph4: K(t+2).{A0,B1}
// vmcnt: entry outstanding 6 = K(t+1).{B0,A0,B1}; +2+2+4 = 14 -> vmcnt(6)
// retires 8 oldest = all of K(t+1); vmcnt(0) at t==NT-2.
// SINGLE BARRIER PER PHASE (R6->R7): the pre-MFMA barrier is redundant --
// every phase's ds_reads are lgkm(0)-drained BEFORE that wave's end-of-phase
// barrier, so a stage issued after the PREVIOUS phase's barrier cannot WAR any
// read; no phase stages a region it reads; vmcnt(6/0) sits before the barrier
// so staged-data RAW is collective. 4 barriers/K-tile; waves de-phase within a
// phase -> cross-wave MFMA||ds_read overlap (was the 22.5% MfmaUtil stall).
// T2 SWIZZLE (rule #21 both-sides): LDS dest LINEAR (gl_lds16), global source
// col pre-swizzled chunk=(tid&7)^((tid>>3)&7); ds_read chunk=(ks*4+lgrp)^(lrow&7).
template<int KSTR>
__device__ __forceinline__ void stage_ht(const bf16* __restrict__ P,
                                         int grow0, bf16* lbase, int tid, int kt){
  const int r = tid >> 3;
  const int c = ((tid & 7) ^ (r & 7)) * 8;      // pre-swizzled source column
  const bf16* g = P + (size_t)(grow0 + r) * KSTR + kt * 64 + c;
  bf16* l = lbase + r * 64 + (tid & 7) * 8;     // linear dest (wave base + lane*16B)
  gl_lds16(g, l);
  gl_lds16(g + (size_t)64 * KSTR, l + 4096);
}

template<int MODE, int KEXT, int KSTR = KEXT>
__global__ __launch_bounds__(512, 2) void gemm8_bt(const bf16* __restrict__ A,
    const bf16* __restrict__ Wt, const float* __restrict__ bias,
    bf16* __restrict__ out_b, float* __restrict__ out_f, float* __restrict__ out_f2)
{
  constexpr int NT = KEXT / 64;
  extern __shared__ bf16 lds[];
  bf16* As = lds;            // [2][256][64] swizzled
  bf16* Bs = lds + 32768;    // [2][256][64] swizzled
  const int tid = threadIdx.x;
  const int ln = tid & 63, wv = tid >> 6;
  const int lrow = ln & 15, lgrp = ln >> 4;
  const int swz = lrow & 7;
  const int wm = wv >> 2, wn = wv & 3;
  const int m0 = blockIdx.x * 256, n0 = blockIdx.y * 256;

  if constexpr (MODE == M_PART){          // split-K slab select
    const int z = blockIdx.z;
    A  += z * 1024;
    Wt += z * 1024;
  }

  f32x4 acc[8][4] = {};
  bf16x8 aA[4][2], bB0[2][2], bB1[2][2];

  #define LDA(MH) { _Pragma("unroll") for (int mf = 0; mf < 4; mf++) \
    _Pragma("unroll") for (int ks = 0; ks < 2; ks++) \
      aA[mf][ks] = *(const bf16x8*)(As + s*16384 + (wm*128 + (MH)*64 + mf*16 + lrow)*64 + ((ks*4 + lgrp) ^ swz)*8); }
  #define LDB(DST, NH) { _Pragma("unroll") for (int nf = 0; nf < 2; nf++) \
    _Pragma("unroll") for (int ks = 0; ks < 2; ks++) \
      DST[nf][ks] = *(const bf16x8*)(Bs + s*16384 + (wn*64 + (NH)*32 + nf*16 + lrow)*64 + ((ks*4 + lgrp) ^ swz)*8); }
  #define QUAD(BARR, IM0, JN0) { _Pragma("unroll") for (int ks = 0; ks < 2; ks++) \
    _Pragma("unroll") for (int mf = 0; mf < 4; mf++) \
      _Pragma("unroll") for (int nf = 0; nf < 2; nf++) \
        acc[(IM0)+mf][(JN0)+nf] = __builtin_amdgcn_mfma_f32_16x16x32_bf16(aA[mf][ks], BARR[nf][ks], acc[(IM0)+mf][(JN0)+nf], 0, 0, 0); }
  #define SBAR() { __builtin_amdgcn_sched_barrier(0); __builtin_amdgcn_s_barrier(); __builtin_amdgcn_sched_barrier(0); }
  #define LGKM0() { asm volatile("s_waitcnt lgkmcnt(0)" ::: "memory"); __builtin_amdgcn_sched_barrier(0); }

  // ---- prologue (order-insensitive): K0 all 4 half-tiles, drain, barrier
  stage_ht<KSTR>(A,  m0,       As,        tid, 0);
  stage_ht<KSTR>(Wt, n0,       Bs,        tid, 0);
  stage_ht<KSTR>(Wt, n0 + 128, Bs + 8192, tid, 0);
  stage_ht<KSTR>(A,  m0 + 128, As + 8192, tid, 0);
  asm volatile("s_waitcnt vmcnt(0)" ::: "memory");
  SBAR();
  // K1.{B0,A0,B1} in flight (retired as a group)
  stage_ht<KSTR>(Wt, n0,       Bs + 16384,        tid, 1);
  stage_ht<KSTR>(A,  m0,       As + 16384,        tid, 1);
  stage_ht<KSTR>(Wt, n0 + 128, Bs + 16384 + 8192, tid, 1);

  for (int t = 0; t < NT; ++t){
    const int s = t & 1;
    const int sx = s ^ 1;
    // ---- phase 1: reads A0+B0; stage K(t+1).A1 -> slot sx; quad(0,0)
    LDA(0); LDB(bB0, 0);
    if (t + 1 < NT) stage_ht<KSTR>(A, m0 + 128, As + sx*16384 + 8192, tid, t + 1);
    LGKM0();
    __builtin_amdgcn_s_setprio(1); QUAD(bB0, 0, 0); __builtin_amdgcn_s_setprio(0);
    SBAR();
    // ---- phase 2: reads B1; NO stage (A0 rows 64-127 live for ph3's LDA(1)); quad(0,1)
    LDB(bB1, 1);
    LGKM0();
    __builtin_amdgcn_s_setprio(1); QUAD(bB1, 0, 2); __builtin_amdgcn_s_setprio(0);
    SBAR();
    // ---- phase 3: reads A1; stage K(t+2).B0 -> slot s (B0 dead after ph1-read); quad(1,1)
    LDA(1);
    if (t + 2 < NT) stage_ht<KSTR>(Wt, n0, Bs + s*16384, tid, t + 2);
    LGKM0();
    __builtin_amdgcn_s_setprio(1); QUAD(bB1, 4, 2); __builtin_amdgcn_s_setprio(0);
    SBAR();
    // ---- phase 4: no reads; stage K(t+2).{A0,B1} -> slot s (A0 dead after ph3); quad(1,0)
    if (t + 2 < NT){
      stage_ht<KSTR>(A,  m0,       As + s*16384,        tid, t + 2);
      stage_ht<KSTR>(Wt, n0 + 128, Bs + s*16384 + 8192, tid, t + 2);
    }
    __builtin_amdgcn_s_setprio(1); QUAD(bB0, 4, 0); __builtin_amdgcn_s_setprio(0);
    if (t == NT - 2)      { asm volatile("s_waitcnt vmcnt(0)" ::: "memory"); }
    else if (t < NT - 2)  { asm volatile("s_waitcnt vmcnt(6)" ::: "memory"); }
    SBAR();
  }
  #undef LDA
  #undef LDB
  #undef QUAD
  #undef SBAR
  #undef LGKM0

  // ---- epilogue
  bf16* pdstb = nullptr;
  if constexpr (MODE == M_PART)
    pdstb = blockIdx.z ? (bf16*)out_f2 : (bf16*)out_f;   // bf16 split-K partials
  #pragma unroll
  for (int im = 0; im < 8; im++){
    #pragma unroll
    for (int jn = 0; jn < 4; jn++){
      const int col = n0 + wn*64 + (jn >> 1)*32 + (jn & 1)*16 + lrow;
      const int row_b = m0 + wm*128 + (im >> 2)*64 + (im & 3)*16 + lgrp*4;
      const float bv = (MODE == M_PART) ? 0.f : bias[col];
      #pragma unroll
      for (int rr = 0; rr < 4; rr++){
        const int row = row_b + rr;
        float v = acc[im][jn][rr] + bv;
        if constexpr (MODE == M_QKV){
          const int t = col >> 9, rem = col & 511;
          const int head = rem >> 5, hd = rem & 31;
          const int win = row >> 6, l = row & 63;
          out_b[(size_t)t * (TOK*DIMM) + ((size_t)(win*NHEAD + head)*WLEN + l)*HDIM + hd]
              = __float2bfloat16(v);
        } else if constexpr (MODE == M_MLP1){
          const float u = 1.5957691216057308f * (v + 0.044715f*v*v*v);
          const float g = v * (1.0f / (1.0f + __expf(-u)));
          out_b[(size_t)row*HID + col] = __float2bfloat16(g);
        } else if constexpr (MODE == M_PART){
          pdstb[(size_t)row*DIMM + col] = __float2bfloat16(v);  // raw partial
        } else { // M_MLP2 (unused now)
          out_f[(size_t)row*DIMM + col] = 2.f * v;
        }
      }
    }
  }
}

// ---------------- MLP2 split-K reduce: d_out = 2*(p0 + p1 + bias), 8 elems/thread ----
__global__ __launch_bounds__(256) void mlp2_reduce(const bf16* __restrict__ p0,
    const bf16* __restrict__ p1, float* __restrict__ dout, const float* __restrict__ bias){
  const size_t i = (size_t)(blockIdx.x * 256 + threadIdx.x) * 8;
  int4 a = *(const int4*)(p0 + i);
  int4 b = *(const int4*)(p1 + i);
  const int cb = (int)(i & 511);
  const float4 bv0 = *(const float4*)(bias + cb);
  const float4 bv1 = *(const float4*)(bias + cb + 4);
  const bf16* ah = (const bf16*)&a;
  const bf16* bh = (const bf16*)&b;
  float4 r0, r1;
  r0.x = 2.f*(__bfloat162float(ah[0]) + __bfloat162float(bh[0]) + bv0.x);
  r0.y = 2.f*(__bfloat162float(ah[1]) + __bfloat162float(bh[1]) + bv0.y);
  r0.z = 2.f*(__bfloat162float(ah[2]) + __bfloat162float(bh[2]) + bv0.z);
  r0.w = 2.f*(__bfloat162float(ah[3]) + __bfloat162float(bh[3]) + bv0.w);
  r1.x = 2.f*(__bfloat162float(ah[4]) + __bfloat162float(bh[4]) + bv1.x);
  r1.y = 2.f*(__bfloat162float(ah[5]) + __bfloat162float(bh[5]) + bv1.y);
  r1.z = 2.f*(__bfloat162float(ah[6]) + __bfloat162float(bh[6]) + bv1.z);
  r1.w = 2.f*(__bfloat162float(ah[7]) + __bfloat162float(bh[7]) + bv1.w);
  *(float4*)(dout + i)     = r0;
  *(float4*)(dout + i + 4) = r1;
}

// ---------------- windowed attention: one wave per (window, head) --------------------
__global__ __launch_bounds__(256) void attn_kernel(const bf16* __restrict__ qkv,
    const float* __restrict__ rpb, bf16* __restrict__ outp)
{
  __shared__ bf16 Pl[4][64][72];
  const int wave = threadIdx.x >> 6, lane = threadIdx.x & 63;
  const int lrow = lane & 15, lgrp = lane >> 4;
  const int wh = blockIdx.x * 4 + wave;
  const int win = wh >> 4, head = wh & 15;
  const bf16* qb = qkv + (size_t)wh * (WLEN*HDIM);
  const bf16* kb = qb + (size_t)TOK * DIMM;
  const bf16* vb = kb + (size_t)TOK * DIMM;

  bf16x8 aq[4], ak[4];
  #pragma unroll
  for (int i = 0; i < 4; i++){
    aq[i] = *(const bf16x8*)(qb + (i*16 + lrow)*HDIM + lgrp*8);
    ak[i] = *(const bf16x8*)(kb + (i*16 + lrow)*HDIM + lgrp*8);
  }
  f32x4 s[4][4] = {};
  #pragma unroll
  for (int i = 0; i < 4; i++)
    #pragma unroll
    for (int j = 0; j < 4; j++)
      s[i][j] = __builtin_amdgcn_mfma_f32_16x16x32_bf16(aq[i], ak[j], s[i][j], 0, 0, 0);

  #pragma unroll
  for (int i = 0; i < 4; i++){
    #pragma unroll
    for (int rr = 0; rr < 4; rr++){
      const int srow = i*16 + lgrp*4 + rr;
      const int rq = region_of(win, srow);
      float vals[4]; float mx = -1e30f;
      #pragma unroll
      for (int j = 0; j < 4; j++){
        const int scol = j*16 + lrow;
        const int idx = ((srow>>3) - (scol>>3) + 7)*15 + ((srow&7) - (scol&7) + 7);
        float v = s[i][j][rr]*SCL + rpb[idx*NHEAD + head];
        if (region_of(win, scol) != rq) v -= 100.f;
        vals[j] = v; mx = fmaxf(mx, v);
      }
      mx = fmaxf(mx, __shfl_xor(mx, 1));
      mx = fmaxf(mx, __shfl_xor(mx, 2));
      mx = fmaxf(mx, __shfl_xor(mx, 4));
      mx = fmaxf(mx, __shfl_xor(mx, 8));
      float sum = 0.f;
      #pragma unroll
      for (int j = 0; j < 4; j++){ vals[j] = __expf(vals[j] - mx); sum += vals[j]; }
      sum += __shfl_xor(sum, 1); sum += __shfl_xor(sum, 2);
      sum += __shfl_xor(sum, 4); sum += __shfl_xor(sum, 8);
      const float rs = 1.f / sum;
      #pragma unroll
      for (int j = 0; j < 4; j++)
        Pl[wave][srow][j*16 + lrow] = __float2bfloat16(vals[j] * rs);
    }
  }

  f32x4 o[4][2] = {};
  const __bf16* vraw = (const __bf16*)vb;
  #pragma unroll
  for (int st = 0; st < 2; st++){
    bf16x8 pa[4];
    #pragma unroll
    for (int i = 0; i < 4; i++)
      pa[i] = *(const bf16x8*)(&Pl[wave][i*16 + lrow][st*32 + lgrp*8]);
    bf16x8 bv[2];
    #pragma unroll
    for (int j = 0; j < 2; j++){
      #pragma unroll
      for (int jj = 0; jj < 8; jj++)
        bv[j][jj] = vraw[(size_t)(st*32 + lgrp*8 + jj)*HDIM + j*16 + lrow];
    }
    #pragma unroll
    for (int i = 0; i < 4; i++)
      #pragma unroll
      for (int j = 0; j < 2; j++)
        o[i][j] = __builtin_amdgcn_mfma_f32_16x16x32_bf16(pa[i], bv[j], o[i][j], 0, 0, 0);
  }
  bf16* orow = outp + (size_t)win * WLEN * DIMM + head * HDIM;
  #pragma unroll
  for (int i = 0; i < 4; i++)
    #pragma unroll
    for (int j = 0; j < 2; j++)
      #pragma unroll
      for (int rr = 0; rr < 4; rr++){
        const int l = i*16 + lgrp*4 + rr;
        orow[(size_t)l * DIMM + j*16 + lrow] = __float2bfloat16(o[i][j][rr]);
      }
}

// ---------------- host launch --------------------------------------------------------
extern "C" void kernel_launch(void* const* d_in, const int* in_sizes, int n_in,
                              void* d_out, int out_size, void* d_ws, size_t ws_size,
                              hipStream_t stream) {
  const float* x     = (const float*)d_in[0];
  const float* ln1w  = (const float*)d_in[1];
  const float* ln1b  = (const float*)d_in[2];
  const float* ln2w  = (const float*)d_in[3];
  const float* ln2b  = (const float*)d_in[4];
  const float* qkvw  = (const float*)d_in[5];
  const float* qkvbi = (const float*)d_in[6];
  const float* projw = (const float*)d_in[7];
  const float* projb = (const float*)d_in[8];
  const float* rpb   = (const float*)d_in[9];
  const float* m1w   = (const float*)d_in[10];
  const float* m1b   = (const float*)d_in[11];
  const float* m2w   = (const float*)d_in[12];
  const float* m2b   = (const float*)d_in[13];

  bf16* wqkv  = (bf16*)d_ws;                 // 786432
  bf16* wproj = wqkv + 786432;               // 262144
  bf16* wm1   = wproj + 262144;              // 1048576
  bf16* wm2   = wm1 + 1048576;               // 1048576
  bf16* xw    = wm2 + 1048576;               // 8388608  (LN1 out / LN2 out / MLP2 p1)
  float* hbuf = (float*)(xw + 8388608);      // 8388608 f32 (attn residual / MLP2 p0)
  bf16* qkvb  = (bf16*)(hbuf + 8388608);     // 3*8388608 (q,k,v)
  bf16* attno = qkvb + 3*(size_t)8388608;    // 8388608
  bf16* m1buf = qkvb;                        // reuse qkv+attno region (MLP1 out 33.5M)
  bf16* h2    = xw;                          // reuse xw (LN2 out)

  hipFuncSetAttribute((const void*)&gemm8_bt<M_QKV, 512>,
                      hipFuncAttributeMaxDynamicSharedMemorySize, 131072);
  hipFuncSetAttribute((const void*)&gemm8_bt<M_MLP1, 512>,
                      hipFuncAttributeMaxDynamicSharedMemorySize, 131072);
  hipFuncSetAttribute((const void*)&gemm8_bt<M_PART, 1024, 2048>,
                      hipFuncAttributeMaxDynamicSharedMemorySize, 131072);

  convert_w<<<3072, 256, 0, stream>>>(qkvw, projw, m1w, m2w, wqkv);
  ln_kernel<true><<<4096, 256, 0, stream>>>(x, ln1w, ln1b, xw);
  { dim3 g(TOK/256, 1536/256);
    gemm8_bt<M_QKV, 512><<<g, 512, 131072, stream>>>(xw, wqkv, qkvbi, qkvb, nullptr, nullptr); }
  attn_kernel<<<1024, 256, 0, stream>>>(qkvb, rpb, attno);
  { dim3 g(TOK/128, 512/128);
    gemm_bt<M_PROJ, 512><<<g, 256, 0, stream>>>(attno, wproj, projb, nullptr, hbuf, x); }
  ln_kernel<false><<<4096, 256, 0, stream>>>(hbuf, ln2w, ln2b, h2);
  { dim3 g(TOK/256, 2048/256);
    gemm8_bt<M_MLP1, 512><<<g, 512, 131072, stream>>>(h2, wm1, m1b, m1buf, nullptr, nullptr); }
  // MLP2 split-K=2, bf16 partials: slab0 -> hbuf region, slab1 -> xw region
  // (both dead: hbuf after LN2 read, xw/h2 after MLP1 read)
  { dim3 g(TOK/256, 512/256, 2);
    gemm8_bt<M_PART, 1024, 2048><<<g, 512, 131072, stream>>>(m1buf, wm2, m2b, nullptr,
                                                             (float*)hbuf, (float*)xw); }
  mlp2_reduce<<<8388608/8/256, 256, 0, stream>>>((const bf16*)hbuf, (const bf16*)xw,
                                                 (float*)d_out, m2b);
}